// Round 5
// baseline (189.689 us; speedup 1.0000x reference)
//
#include <hip/hip_runtime.h>
#include <hip/hip_bf16.h>
#include <math.h>

#define DIM 512
#define NH 8
#define HD 64
#define TT 1024
#define CH 32      // chunks per (b,h) sequence
#define CL 32      // chunk length (CH*CL == TT)
#define BK 32      // GEMM k-tile
#define EPSF 1e-5f
#define LN2F 0.69314718056f
#define LOG2EF 1.44269504089f

// raw gfx950 hardware transcendentals: v_exp_f32 = 2^x, v_log_f32 = log2(x)
__device__ __forceinline__ float fexp2(float x) { return __builtin_amdgcn_exp2f(x); }
__device__ __forceinline__ float flog2(float x) { return __builtin_amdgcn_logf(x); }

// Linear-space scan reformulation (see round-4 notes):
//   num[t,q] = sum_p Qf[t,p]*ln A[t,p,q] - c1,  den[t] = sum_p Qf*(ln A_D - m_c) + eps
//   staged: Vv2 = v*log2e, Qf2 = Qf*ln2, m02 = log2(Kf+eps)

// ---------------- GEMM v2: 64x64 tile, 128 thr, 8x4/thread, BK=32, dbuf ----------
// A-stage: thread (tid&63)=row, (tid>>6)*16=k-off, 64B contiguous/lane.
// B-stage: thread (tid>>4)=krow(+8g), (tid&15)*4=col, 16-lane row sweeps.
// LDS padded to 68 -> write conflicts <=2-way (free). One barrier per k-tile.

__launch_bounds__(128)
__global__ void k_gemm_qkv(const float* __restrict__ x,
                           const float* __restrict__ wq, const float* __restrict__ bq,
                           const float* __restrict__ wk, const float* __restrict__ bk,
                           const float* __restrict__ wv, const float* __restrict__ bv,
                           const float* __restrict__ lbeta, const float* __restrict__ ltemp,
                           float* __restrict__ Qf2, float* __restrict__ Kf, float* __restrict__ Vv2)
{
    const int z = blockIdx.z;
    const float* __restrict__ w    = (z == 0) ? wq : (z == 1) ? wk : wv;
    const float* __restrict__ bias = (z == 0) ? bq : (z == 1) ? bk : bv;
    const int h = blockIdx.x;
    const int rowBase = blockIdx.y * 64;
    const int colBase = h * 64;

    __shared__ __align__(16) float As[2][BK][68];
    __shared__ __align__(16) float Bs[2][BK][68];

    const int tid = threadIdx.x;             // 0..127
    const int tx = tid & 15, ty = tid >> 4;  // ty 0..7
    const int r0 = ty * 8, c0 = tx * 4;

    const int arow = tid & 63;               // A staging row
    const int ak0  = (tid >> 6) * 16;        // A staging k-offset (0 or 16)
    const int brow = tid >> 4;               // B staging base k-row (0..7)
    const int bc4  = (tid & 15) * 4;         // B staging col

    const float* ax = x + (size_t)(rowBase + arow) * DIM + ak0;
    const float* bw = w + (size_t)brow * DIM + colBase + bc4;

    float4 ra[4], rb[4];
#define LOADT(K0) { \
    const float* ap = ax + (K0); \
    ra[0] = *(const float4*)&ap[0];  ra[1] = *(const float4*)&ap[4]; \
    ra[2] = *(const float4*)&ap[8];  ra[3] = *(const float4*)&ap[12]; \
    const float* bp = bw + (size_t)(K0) * DIM; \
    rb[0] = *(const float4*)&bp[0]; \
    rb[1] = *(const float4*)&bp[8 * DIM]; \
    rb[2] = *(const float4*)&bp[16 * DIM]; \
    rb[3] = *(const float4*)&bp[24 * DIM]; }

    LOADT(0)
    float acc[8][4] = {};

    for (int it = 0; it < DIM / BK; ++it) {
        const int cur = it & 1;
#pragma unroll
        for (int j = 0; j < 16; j++)
            As[cur][ak0 + j][arow] = ((const float*)ra)[j];
#pragma unroll
        for (int g = 0; g < 4; g++)
            *(float4*)&Bs[cur][brow + 8 * g][bc4] = rb[g];
        __syncthreads();
        if (it + 1 < DIM / BK) { LOADT((it + 1) * BK) }
#pragma unroll
        for (int kk = 0; kk < BK; kk++) {
            float4 a0 = *(const float4*)&As[cur][kk][r0];
            float4 a1 = *(const float4*)&As[cur][kk][r0 + 4];
            float4 b0 = *(const float4*)&Bs[cur][kk][c0];
            float aa[8] = {a0.x,a0.y,a0.z,a0.w,a1.x,a1.y,a1.z,a1.w};
            float bb[4] = {b0.x,b0.y,b0.z,b0.w};
#pragma unroll
            for (int i = 0; i < 8; i++)
#pragma unroll
                for (int j = 0; j < 4; j++)
                    acc[i][j] = fmaf(aa[i], bb[j], acc[i][j]);
        }
    }

    float b4[4] = { bias[colBase + c0 + 0], bias[colBase + c0 + 1],
                    bias[colBase + c0 + 2], bias[colBase + c0 + 3] };

    if (z == 2) {
#pragma unroll
        for (int i = 0; i < 8; i++) {
            int rr = rowBase + r0 + i;
            int bbn = rr >> 10, t = rr & (TT - 1);
            float4 o;
            o.x = (acc[i][0] + b4[0]) * LOG2EF; o.y = (acc[i][1] + b4[1]) * LOG2EF;
            o.z = (acc[i][2] + b4[2]) * LOG2EF; o.w = (acc[i][3] + b4[3]) * LOG2EF;
            *(float4*)&Vv2[(((size_t)(bbn * NH + h)) * TT + t) * HD + c0] = o;
        }
    } else {
        float beta = expf(lbeta[h]);
        float itemp = 1.0f / expf(ltemp[h]);
        float oscale = (z == 0) ? (LN2F / beta) : (1.0f / beta);
        float* __restrict__ dst = (z == 0) ? Qf2 : Kf;
#pragma unroll
        for (int i = 0; i < 8; i++) {
            int rr = rowBase + r0 + i;
            int bbn = rr >> 10, t = rr & (TT - 1);
            float v4[4];
#pragma unroll
            for (int j = 0; j < 4; j++) {
                float val = (acc[i][j] + b4[j]) * itemp;
                float zz = beta * val;
                v4[j] = (fmaxf(zz, 0.f) + log1pf(expf(-fabsf(zz)))) * oscale;
            }
            float4 o = { v4[0], v4[1], v4[2], v4[3] };
            *(float4*)&dst[(((size_t)(bbn * NH + h)) * TT + t) * HD + c0] = o;
        }
    }
#undef LOADT
}

// ---------------- Kernel 2: per-chunk local sums ----------------
__launch_bounds__(256)
__global__ void k_chunk_reduce(const float* __restrict__ Kf, const float* __restrict__ Vv2,
                               float* __restrict__ aA, float* __restrict__ aD,
                               float* __restrict__ aCM)
{
    const int c = blockIdx.x >> 1, qh = blockIdx.x & 1;
    const int bh = blockIdx.z * NH + blockIdx.y;
    const int tid = threadIdx.x;

    __shared__ __align__(16) float sK[CL * HD];
    __shared__ __align__(16) float sV2[CL * HD];
    __shared__ __align__(16) float sM02[CL * HD];

    size_t base = ((size_t)bh * TT + (size_t)c * CL) * HD;
    const float4* K4 = (const float4*)(Kf + base);
    const float4* V4 = (const float4*)(Vv2 + base);
#pragma unroll
    for (int r = 0; r < 2; r++) {
        int f = tid + 256 * r;
        float4 kv = K4[f];
        ((float4*)sK)[f] = kv;
        float4 m;
        m.x = flog2(kv.x + EPSF); m.y = flog2(kv.y + EPSF);
        m.z = flog2(kv.z + EPSF); m.w = flog2(kv.w + EPSF);
        ((float4*)sM02)[f] = m;
        ((float4*)sV2)[f] = V4[f];
    }
    __syncthreads();

    const int p = tid & 63, qo = tid >> 6;
    const int q0 = qh * 32 + qo * 8;
    float A[8] = {};
    float AD = 0.f, cmx = 0.f;
    const bool doD = (qh == 0) && (tid < 64);

    for (int s = 0; s < CL; s++) {
        float vp = sV2[s * HD + p];
        float mp = sM02[s * HD + p];
        float4 ka = *(const float4*)&sK[s * HD + q0];
        float4 kb = *(const float4*)&sK[s * HD + q0 + 4];
        A[0] += fexp2(fmaf(vp, ka.x, mp));
        A[1] += fexp2(fmaf(vp, ka.y, mp));
        A[2] += fexp2(fmaf(vp, ka.z, mp));
        A[3] += fexp2(fmaf(vp, ka.w, mp));
        A[4] += fexp2(fmaf(vp, kb.x, mp));
        A[5] += fexp2(fmaf(vp, kb.y, mp));
        A[6] += fexp2(fmaf(vp, kb.z, mp));
        A[7] += fexp2(fmaf(vp, kb.w, mp));
        if (doD) {
            float kn = sK[s * HD + tid];
            float mn = sM02[s * HD + tid];
            AD += fexp2(fmaf(kn, LOG2EF, mn));
            cmx = fmaxf(cmx, kn + EPSF);
        }
    }

    size_t abase = ((size_t)bh * CH + c) * 4096 + (size_t)p * HD + q0;
    float4 o0 = { A[0], A[1], A[2], A[3] };
    float4 o1 = { A[4], A[5], A[6], A[7] };
    *(float4*)&aA[abase] = o0;
    *(float4*)&aA[abase + 4] = o1;
    if (doD) {
        size_t dbase = ((size_t)bh * CH + c) * HD + tid;
        aD[dbase] = AD; aCM[dbase] = cmx;
    }
}

// ---------------- Kernel 3: exclusive scan of chunk aggregates ----------------
__global__ void k_scan_agg(float* __restrict__ aA, float* __restrict__ aD,
                           float* __restrict__ aCM, int BH)
{
    int idx = blockIdx.x * 256 + threadIdx.x;
    int nA = BH * 4096, nD = BH * 64;
    if (idx < nA) {
        int bh = idx >> 12, pn = idx & 4095;
        float Sr = 0.f;
        for (int c = 0; c < CH; c++) {
            size_t off = ((size_t)bh * CH + c) * 4096 + pn;
            float t = aA[off]; aA[off] = Sr; Sr += t;
        }
    } else if (idx < nA + nD) {
        int i = idx - nA; int bh = i >> 6, n = i & 63;
        float Sr = 0.f;
        for (int c = 0; c < CH; c++) {
            size_t off = ((size_t)bh * CH + c) * HD + n;
            float t = aD[off]; aD[off] = Sr; Sr += t;
        }
    } else if (idx < nA + 2 * nD) {
        int i = idx - nA - nD; int bh = i >> 6, n = i & 63;
        float r = 0.f;
        for (int c = 0; c < CH; c++) {
            size_t off = ((size_t)bh * CH + c) * HD + n;
            float v = aCM[off]; aCM[off] = r; r = fmaxf(r, v);
        }
    }
}

// ---------------- Kernel 4: denominator / c1 per t ----------------
__launch_bounds__(64)
__global__ void k_den(const float* __restrict__ Kf, const float* __restrict__ Qf2,
                      const float* __restrict__ aD, const float* __restrict__ aCM,
                      float* __restrict__ c1f, float* __restrict__ invd)
{
    const int c = blockIdx.x;
    const int bh = blockIdx.z * NH + blockIdx.y;
    const int n = threadIdx.x;
    size_t dbase = ((size_t)bh * CH + c) * HD + n;
    float AD = aD[dbase], cmx = aCM[dbase];
    size_t base = ((size_t)bh * TT + (size_t)c * CL) * HD + n;
    float* outc = c1f + (size_t)bh * TT + c * CL;
    float* outi = invd + (size_t)bh * TT + c * CL;

    for (int s = 0; s < CL; s++) {
        float kn = Kf[base + (size_t)s * HD];
        float qn = Qf2[base + (size_t)s * HD];
        float mn = flog2(kn + EPSF);
        AD += fexp2(fmaf(kn, LOG2EF, mn));
        cmx = fmaxf(cmx, kn + EPSF);
        float t1 = qn * flog2(cmx);
        float t2 = qn * flog2(AD);
#pragma unroll
        for (int off = 1; off <= 32; off <<= 1) {
            t1 += __shfl_xor(t1, off);
            t2 += __shfl_xor(t2, off);
        }
        if (n == 0) {
            outc[s] = t1;
            outi[s] = 1.0f / (t2 - t1 + EPSF);
        }
    }
}

// ---------------- Kernel 5: within-chunk rescan + output Y ----------------
__launch_bounds__(256)
__global__ void k_chunk_out(const float* __restrict__ Kf, const float* __restrict__ Vv2,
                            const float* __restrict__ Qf2, const float* __restrict__ aA,
                            const float* __restrict__ c1f, const float* __restrict__ invd,
                            const float* __restrict__ lsharp, float* __restrict__ Ym)
{
    const int c = blockIdx.x, hh = blockIdx.y, bb = blockIdx.z;
    const int bh = bb * NH + hh;
    const int tid = threadIdx.x;

    __shared__ __align__(16) float sK[CL * HD];
    __shared__ __align__(16) float sV2[CL * HD];
    __shared__ __align__(16) float sM02[CL * HD];
    __shared__ __align__(16) float sQ2[CL * HD];

    size_t base = ((size_t)bh * TT + (size_t)c * CL) * HD;
    const float4* K4 = (const float4*)(Kf + base);
    const float4* V4 = (const float4*)(Vv2 + base);
    const float4* Q4 = (const float4*)(Qf2 + base);
#pragma unroll
    for (int r = 0; r < 2; r++) {
        int f = tid + 256 * r;
        float4 kv = K4[f];
        ((float4*)sK)[f] = kv;
        float4 m;
        m.x = flog2(kv.x + EPSF); m.y = flog2(kv.y + EPSF);
        m.z = flog2(kv.z + EPSF); m.w = flog2(kv.w + EPSF);
        ((float4*)sM02)[f] = m;
        ((float4*)sV2)[f] = V4[f];
        ((float4*)sQ2)[f] = Q4[f];
    }
    __syncthreads();

    const int lane = tid & 63, w = tid >> 6;
    const int g = lane >> 3, qil = lane & 7;
    const int qA = w * 8 + qil, qB = qA + 32;
    const int p0 = g * 8;

    float A[8], Bq[8];
    size_t abase = ((size_t)bh * CH + c) * 4096;
#pragma unroll
    for (int j = 0; j < 8; j++) {
        A[j]  = aA[abase + (size_t)(p0 + j) * HD + qA];
        Bq[j] = aA[abase + (size_t)(p0 + j) * HD + qB];
    }
    const float sharp = expf(lsharp[hh]);
    const float invT = 1.0f / (float)TT;
    const float* c1p = c1f + (size_t)bh * TT + c * CL;
    const float* ivp = invd + (size_t)bh * TT + c * CL;

    for (int s = 0; s < CL; s++) {
        float kqA = sK[s * HD + qA];
        float kqB = sK[s * HD + qB];
        float partA = 0.f, partB = 0.f;
#pragma unroll
        for (int j4 = 0; j4 < 2; j4++) {
            float4 vv = *(const float4*)&sV2[s * HD + p0 + j4 * 4];
            float4 mm = *(const float4*)&sM02[s * HD + p0 + j4 * 4];
            float4 qv = *(const float4*)&sQ2[s * HD + p0 + j4 * 4];
#define STEP(comp, jj) { \
            A[jj]  += fexp2(fmaf(vv.comp, kqA, mm.comp)); \
            partA = fmaf(qv.comp, flog2(A[jj]), partA); \
            Bq[jj] += fexp2(fmaf(vv.comp, kqB, mm.comp)); \
            partB = fmaf(qv.comp, flog2(Bq[jj]), partB); }
            STEP(x, j4 * 4 + 0)
            STEP(y, j4 * 4 + 1)
            STEP(z, j4 * 4 + 2)
            STEP(w, j4 * 4 + 3)
#undef STEP
        }
        partA += __shfl_xor(partA, 8);
        partA += __shfl_xor(partA, 16);
        partA += __shfl_xor(partA, 32);
        partB += __shfl_xor(partB, 8);
        partB += __shfl_xor(partB, 16);
        partB += __shfl_xor(partB, 32);

        float c1v = c1p[s], iv = ivp[s];
        int tg = c * CL + s;
        float scale = (float)(tg + 1) * invT;
        float yA = (partA - c1v) * iv;
        float yB = (partB - c1v) * iv;
        float oA = copysignf(fexp2(sharp * flog2(fabsf(yA))), yA) * scale;
        float oB = copysignf(fexp2(sharp * flog2(fabsf(yB))), yB) * scale;
        if (g == 0) {
            float* yrow = Ym + ((size_t)(bb * TT + tg)) * DIM + hh * HD;
            yrow[qA] = oA;
            yrow[qB] = oB;
        }
    }
}

// ---------------- Kernel 6: output projection (GEMM v2) ----------------
__launch_bounds__(128)
__global__ void k_gemm_out(const float* __restrict__ A, const float* __restrict__ w,
                           const float* __restrict__ bias, float* __restrict__ out)
{
    const int rowBase = blockIdx.y * 64;
    const int colBase = blockIdx.x * 64;

    __shared__ __align__(16) float As[2][BK][68];
    __shared__ __align__(16) float Bs[2][BK][68];

    const int tid = threadIdx.x;
    const int tx = tid & 15, ty = tid >> 4;
    const int r0 = ty * 8, c0 = tx * 4;

    const int arow = tid & 63;
    const int ak0  = (tid >> 6) * 16;
    const int brow = tid >> 4;
    const int bc4  = (tid & 15) * 4;

    const float* ax = A + (size_t)(rowBase + arow) * DIM + ak0;
    const float* bw = w + (size_t)brow * DIM + colBase + bc4;

    float4 ra[4], rb[4];
#define LOADT(K0) { \
    const float* ap = ax + (K0); \
    ra[0] = *(const float4*)&ap[0];  ra[1] = *(const float4*)&ap[4]; \
    ra[2] = *(const float4*)&ap[8];  ra[3] = *(const float4*)&ap[12]; \
    const float* bp = bw + (size_t)(K0) * DIM; \
    rb[0] = *(const float4*)&bp[0]; \
    rb[1] = *(const float4*)&bp[8 * DIM]; \
    rb[2] = *(const float4*)&bp[16 * DIM]; \
    rb[3] = *(const float4*)&bp[24 * DIM]; }

    LOADT(0)
    float acc[8][4] = {};

    for (int it = 0; it < DIM / BK; ++it) {
        const int cur = it & 1;
#pragma unroll
        for (int j = 0; j < 16; j++)
            As[cur][ak0 + j][arow] = ((const float*)ra)[j];
#pragma unroll
        for (int g = 0; g < 4; g++)
            *(float4*)&Bs[cur][brow + 8 * g][bc4] = rb[g];
        __syncthreads();
        if (it + 1 < DIM / BK) { LOADT((it + 1) * BK) }
#pragma unroll
        for (int kk = 0; kk < BK; kk++) {
            float4 a0 = *(const float4*)&As[cur][kk][r0];
            float4 a1 = *(const float4*)&As[cur][kk][r0 + 4];
            float4 b0 = *(const float4*)&Bs[cur][kk][c0];
            float aa[8] = {a0.x,a0.y,a0.z,a0.w,a1.x,a1.y,a1.z,a1.w};
            float bb[4] = {b0.x,b0.y,b0.z,b0.w};
#pragma unroll
            for (int i = 0; i < 8; i++)
#pragma unroll
                for (int j = 0; j < 4; j++)
                    acc[i][j] = fmaf(aa[i], bb[j], acc[i][j]);
        }
    }

    float b4[4] = { bias[colBase + c0 + 0], bias[colBase + c0 + 1],
                    bias[colBase + c0 + 2], bias[colBase + c0 + 3] };
#pragma unroll
    for (int i = 0; i < 8; i++) {
        int rr = rowBase + r0 + i;
        float4 o;
        o.x = acc[i][0] + b4[0]; o.y = acc[i][1] + b4[1];
        o.z = acc[i][2] + b4[2]; o.w = acc[i][3] + b4[3];
        *(float4*)&out[(size_t)rr * DIM + colBase + c0] = o;
    }
#undef LOADT
}

extern "C" void kernel_launch(void* const* d_in, const int* in_sizes, int n_in,
                              void* d_out, int out_size, void* d_ws, size_t ws_size,
                              hipStream_t stream)
{
    const float* x  = (const float*)d_in[0];
    const float* wq = (const float*)d_in[1];
    const float* bq = (const float*)d_in[2];
    const float* wk = (const float*)d_in[3];
    const float* bk = (const float*)d_in[4];
    const float* wv = (const float*)d_in[5];
    const float* bv = (const float*)d_in[6];
    const float* wo = (const float*)d_in[7];
    const float* bo = (const float*)d_in[8];
    const float* lb = (const float*)d_in[9];
    const float* lt = (const float*)d_in[10];
    const float* ls = (const float*)d_in[11];

    const int B  = in_sizes[0] / (TT * DIM);   // 2
    const int BH = B * NH;                     // 16

    float* ws   = (float*)d_ws;
    float* Qf2  = ws;
    float* Kf   = Qf2 + (size_t)BH * TT * HD;
    float* Vv2  = Kf  + (size_t)BH * TT * HD;
    float* Ym   = Vv2 + (size_t)BH * TT * HD;
    float* aA   = Ym  + (size_t)B * TT * DIM;
    float* aD   = aA  + (size_t)BH * CH * 4096;
    float* aCM  = aD  + (size_t)BH * CH * HD;
    float* c1f  = aCM + (size_t)BH * CH * HD;
    float* invd = c1f + (size_t)BH * TT;

    dim3 g1(NH, (B * TT) / 64, 3);
    k_gemm_qkv<<<g1, 128, 0, stream>>>(x, wq, bq, wk, bk, wv, bv, lb, lt, Qf2, Kf, Vv2);

    dim3 g2(CH * 2, NH, B);
    k_chunk_reduce<<<g2, 256, 0, stream>>>(Kf, Vv2, aA, aD, aCM);

    int ntot = BH * 4096 + 2 * BH * 64;
    k_scan_agg<<<(ntot + 255) / 256, 256, 0, stream>>>(aA, aD, aCM, BH);

    dim3 g4(CH, NH, B);
    k_den<<<g4, 64, 0, stream>>>(Kf, Qf2, aD, aCM, c1f, invd);

    k_chunk_out<<<g4, 256, 0, stream>>>(Kf, Vv2, Qf2, aA, c1f, invd, ls, Ym);

    dim3 g6(DIM / 64, (B * TT) / 64);
    k_gemm_out<<<g6, 128, 0, stream>>>(Ym, wo, bo, (float*)d_out);
}

// Round 6
// 142.836 us; speedup vs baseline: 1.3280x; 1.3280x over previous
//
#include <hip/hip_runtime.h>
#include <hip/hip_bf16.h>
#include <math.h>

#define DIM 512
#define NH 8
#define HD 64
#define TT 1024
#define CH 32      // chunks per (b,h) sequence
#define CL 32      // chunk length (CH*CL == TT)
#define EPSF 1e-5f
#define LN2F 0.69314718056f
#define LOG2EF 1.44269504089f

typedef unsigned short ushort_t;
typedef __attribute__((ext_vector_type(8))) short bf16x8;
typedef __attribute__((ext_vector_type(4))) float f32x4;

// raw gfx950 hardware transcendentals: v_exp_f32 = 2^x, v_log_f32 = log2(x)
__device__ __forceinline__ float fexp2(float x) { return __builtin_amdgcn_exp2f(x); }
__device__ __forceinline__ float flog2(float x) { return __builtin_amdgcn_logf(x); }

__device__ __forceinline__ ushort_t f2bf(float f) {
    union { float f; unsigned u; } v; v.f = f;
    unsigned r = v.u + 0x7FFFu + ((v.u >> 16) & 1u);
    return (ushort_t)(r >> 16);
}
__device__ __forceinline__ float bf2f(ushort_t h) {
    union { unsigned u; float f; } v; v.u = ((unsigned)h) << 16;
    return v.f;
}

// ---------------- cvt: x -> bf16 hi/lo ----------------
__launch_bounds__(256)
__global__ void k_cvt_x(const float* __restrict__ x, ushort_t* __restrict__ xh,
                        ushort_t* __restrict__ xl)
{
    int i = (blockIdx.x * 256 + threadIdx.x) * 4;
    float4 v = *(const float4*)&x[i];
    ushort4 h, l;
    h.x = f2bf(v.x); l.x = f2bf(v.x - bf2f(h.x));
    h.y = f2bf(v.y); l.y = f2bf(v.y - bf2f(h.y));
    h.z = f2bf(v.z); l.z = f2bf(v.z - bf2f(h.z));
    h.w = f2bf(v.w); l.w = f2bf(v.w - bf2f(h.w));
    *(ushort4*)&xh[i] = h;
    *(ushort4*)&xl[i] = l;
}

// ---------------- cvt: weights -> transposed bf16 [n][k] ----------------
// grid (8 n-tiles, 4 k-tiles, 4 matrices), 256 thr.
// mat 0..2 (wq,wk,wv): hi+lo into wTh/wTl; mat 3 (wo): hi only into wTo.
__launch_bounds__(256)
__global__ void k_cvt_w(const float* __restrict__ wq, const float* __restrict__ wk,
                        const float* __restrict__ wv, const float* __restrict__ wo,
                        ushort_t* __restrict__ wTh, ushort_t* __restrict__ wTl,
                        ushort_t* __restrict__ wTo)
{
    const int mat = blockIdx.z;
    const float* w = (mat == 0) ? wq : (mat == 1) ? wk : (mat == 2) ? wv : wo;
    const int n  = blockIdx.x * 64 + (threadIdx.x & 63);
    const int k0 = blockIdx.y * 128 + (threadIdx.x >> 6) * 32;

    ushort_t hb[32], lb[32];
#pragma unroll
    for (int j = 0; j < 32; j++) {
        float v = w[(size_t)(k0 + j) * DIM + n];
        hb[j] = f2bf(v);
        lb[j] = f2bf(v - bf2f(hb[j]));
    }
    if (mat < 3) {
        ushort_t* dh = wTh + (size_t)mat * DIM * DIM + (size_t)n * DIM + k0;
        ushort_t* dl = wTl + (size_t)mat * DIM * DIM + (size_t)n * DIM + k0;
#pragma unroll
        for (int j = 0; j < 8; j++) {
            ushort4 th = { hb[4*j], hb[4*j+1], hb[4*j+2], hb[4*j+3] };
            ushort4 tl = { lb[4*j], lb[4*j+1], lb[4*j+2], lb[4*j+3] };
            *(ushort4*)&dh[4*j] = th;
            *(ushort4*)&dl[4*j] = tl;
        }
    } else {
        ushort_t* dh = wTo + (size_t)n * DIM + k0;
#pragma unroll
        for (int j = 0; j < 8; j++) {
            ushort4 th = { hb[4*j], hb[4*j+1], hb[4*j+2], hb[4*j+3] };
            *(ushort4*)&dh[4*j] = th;
        }
    }
}

// ---------------- Kernel 1: fused QKV projection via MFMA (hi/lo bf16) -------
// grid (NH, rows/64, 3), 256 thr (4 waves). Wave w: 16 rows x 64 cols.
// A-frag: lane holds A[l&15][(l>>4)*8+j] (16B contiguous from xh/xl).
// B-frag: lane holds B[(l>>4)*8+j][l&15] = wT[col][k..k+8) (16B contiguous).
// D = Ah*Bh + Al*Bh + Ah*Bl  (~2^-17 relative accuracy).
__launch_bounds__(256)
__global__ void k_gemm_qkv(const ushort_t* __restrict__ xh, const ushort_t* __restrict__ xl,
                           const ushort_t* __restrict__ wTh, const ushort_t* __restrict__ wTl,
                           const float* __restrict__ bq, const float* __restrict__ bk,
                           const float* __restrict__ bv,
                           const float* __restrict__ lbeta, const float* __restrict__ ltemp,
                           float* __restrict__ Qf2, float* __restrict__ Kf,
                           float* __restrict__ Vv2)
{
    const int z = blockIdx.z, h = blockIdx.x;
    const int rowBase = blockIdx.y * 64;
    const float* bias = (z == 0) ? bq : (z == 1) ? bk : bv;

    const int tid = threadIdx.x;
    const int w16 = (tid >> 6) * 16;       // wave's row offset in tile
    const int l = tid & 63;
    const int m = l & 15, g = l >> 4;

    const int arow = rowBase + w16 + m;
    const ushort_t* axh = xh + (size_t)arow * DIM + g * 8;
    const ushort_t* axl = xl + (size_t)arow * DIM + g * 8;
    const ushort_t* bwh = wTh + (size_t)z * DIM * DIM + (size_t)(h * 64 + m) * DIM + g * 8;
    const ushort_t* bwl = wTl + (size_t)z * DIM * DIM + (size_t)(h * 64 + m) * DIM + g * 8;

    f32x4 acc[4] = { {0,0,0,0}, {0,0,0,0}, {0,0,0,0}, {0,0,0,0} };

    for (int k0 = 0; k0 < DIM; k0 += 32) {
        bf16x8 ah = *(const bf16x8*)(axh + k0);
        bf16x8 al = *(const bf16x8*)(axl + k0);
#pragma unroll
        for (int n = 0; n < 4; n++) {
            bf16x8 bh = *(const bf16x8*)(bwh + (size_t)n * 16 * DIM + k0);
            bf16x8 bl = *(const bf16x8*)(bwl + (size_t)n * 16 * DIM + k0);
            acc[n] = __builtin_amdgcn_mfma_f32_16x16x32_bf16(ah, bh, acc[n], 0, 0, 0);
            acc[n] = __builtin_amdgcn_mfma_f32_16x16x32_bf16(al, bh, acc[n], 0, 0, 0);
            acc[n] = __builtin_amdgcn_mfma_f32_16x16x32_bf16(ah, bl, acc[n], 0, 0, 0);
        }
    }

    // epilogue: C/D layout col=lane&15, row=(lane>>4)*4+reg  [m89 verified]
    if (z == 2) {
#pragma unroll
        for (int n = 0; n < 4; n++) {
            int c = n * 16 + m;
            float bval = bias[h * 64 + c];
#pragma unroll
            for (int r = 0; r < 4; r++) {
                int rr = rowBase + w16 + g * 4 + r;
                int bb = rr >> 10, t = rr & (TT - 1);
                Vv2[(((size_t)(bb * NH + h)) * TT + t) * HD + c] = (acc[n][r] + bval) * LOG2EF;
            }
        }
    } else {
        float beta = expf(lbeta[h]);
        float itemp = 1.0f / expf(ltemp[h]);
        float oscale = (z == 0) ? (LN2F / beta) : (1.0f / beta);
        float* __restrict__ dst = (z == 0) ? Qf2 : Kf;
#pragma unroll
        for (int n = 0; n < 4; n++) {
            int c = n * 16 + m;
            float bval = bias[h * 64 + c];
#pragma unroll
            for (int r = 0; r < 4; r++) {
                int rr = rowBase + w16 + g * 4 + r;
                int bb = rr >> 10, t = rr & (TT - 1);
                float val = (acc[n][r] + bval) * itemp;
                float zz = beta * val;
                float sp = (fmaxf(zz, 0.f) + log1pf(expf(-fabsf(zz)))) * oscale;
                dst[(((size_t)(bb * NH + h)) * TT + t) * HD + c] = sp;
            }
        }
    }
}

// ---------------- Kernel 2: per-chunk local sums ----------------
__launch_bounds__(256)
__global__ void k_chunk_reduce(const float* __restrict__ Kf, const float* __restrict__ Vv2,
                               float* __restrict__ aA, float* __restrict__ aD,
                               float* __restrict__ aCM)
{
    const int c = blockIdx.x >> 1, qh = blockIdx.x & 1;
    const int bh = blockIdx.z * NH + blockIdx.y;
    const int tid = threadIdx.x;

    __shared__ __align__(16) float sK[CL * HD];
    __shared__ __align__(16) float sV2[CL * HD];
    __shared__ __align__(16) float sM02[CL * HD];

    size_t base = ((size_t)bh * TT + (size_t)c * CL) * HD;
    const float4* K4 = (const float4*)(Kf + base);
    const float4* V4 = (const float4*)(Vv2 + base);
#pragma unroll
    for (int r = 0; r < 2; r++) {
        int f = tid + 256 * r;
        float4 kv = K4[f];
        ((float4*)sK)[f] = kv;
        float4 mm;
        mm.x = flog2(kv.x + EPSF); mm.y = flog2(kv.y + EPSF);
        mm.z = flog2(kv.z + EPSF); mm.w = flog2(kv.w + EPSF);
        ((float4*)sM02)[f] = mm;
        ((float4*)sV2)[f] = V4[f];
    }
    __syncthreads();

    const int p = tid & 63, qo = tid >> 6;
    const int q0 = qh * 32 + qo * 8;
    float A[8] = {};
    float AD = 0.f, cmx = 0.f;
    const bool doD = (qh == 0) && (tid < 64);

    for (int s = 0; s < CL; s++) {
        float vp = sV2[s * HD + p];
        float mp = sM02[s * HD + p];
        float4 ka = *(const float4*)&sK[s * HD + q0];
        float4 kb = *(const float4*)&sK[s * HD + q0 + 4];
        A[0] += fexp2(fmaf(vp, ka.x, mp));
        A[1] += fexp2(fmaf(vp, ka.y, mp));
        A[2] += fexp2(fmaf(vp, ka.z, mp));
        A[3] += fexp2(fmaf(vp, ka.w, mp));
        A[4] += fexp2(fmaf(vp, kb.x, mp));
        A[5] += fexp2(fmaf(vp, kb.y, mp));
        A[6] += fexp2(fmaf(vp, kb.z, mp));
        A[7] += fexp2(fmaf(vp, kb.w, mp));
        if (doD) {
            float kn = sK[s * HD + tid];
            float mn = sM02[s * HD + tid];
            AD += fexp2(fmaf(kn, LOG2EF, mn));
            cmx = fmaxf(cmx, kn + EPSF);
        }
    }

    size_t abase = ((size_t)bh * CH + c) * 4096 + (size_t)p * HD + q0;
    float4 o0 = { A[0], A[1], A[2], A[3] };
    float4 o1 = { A[4], A[5], A[6], A[7] };
    *(float4*)&aA[abase] = o0;
    *(float4*)&aA[abase + 4] = o1;
    if (doD) {
        size_t dbase = ((size_t)bh * CH + c) * HD + tid;
        aD[dbase] = AD; aCM[dbase] = cmx;
    }
}

// ---------------- Kernel 3: exclusive scan of chunk aggregates ----------------
__global__ void k_scan_agg(float* __restrict__ aA, float* __restrict__ aD,
                           float* __restrict__ aCM, int BH)
{
    int idx = blockIdx.x * 256 + threadIdx.x;
    int nA = BH * 4096, nD = BH * 64;
    if (idx < nA) {
        int bh = idx >> 12, pn = idx & 4095;
        float Sr = 0.f;
        for (int c = 0; c < CH; c++) {
            size_t off = ((size_t)bh * CH + c) * 4096 + pn;
            float t = aA[off]; aA[off] = Sr; Sr += t;
        }
    } else if (idx < nA + nD) {
        int i = idx - nA; int bh = i >> 6, n = i & 63;
        float Sr = 0.f;
        for (int c = 0; c < CH; c++) {
            size_t off = ((size_t)bh * CH + c) * HD + n;
            float t = aD[off]; aD[off] = Sr; Sr += t;
        }
    } else if (idx < nA + 2 * nD) {
        int i = idx - nA - nD; int bh = i >> 6, n = i & 63;
        float r = 0.f;
        for (int c = 0; c < CH; c++) {
            size_t off = ((size_t)bh * CH + c) * HD + n;
            float v = aCM[off]; aCM[off] = r; r = fmaxf(r, v);
        }
    }
}

// ---------------- Kernel 4: denominator / c1 per t ----------------
__launch_bounds__(64)
__global__ void k_den(const float* __restrict__ Kf, const float* __restrict__ Qf2,
                      const float* __restrict__ aD, const float* __restrict__ aCM,
                      float* __restrict__ c1f, float* __restrict__ invd)
{
    const int c = blockIdx.x;
    const int bh = blockIdx.z * NH + blockIdx.y;
    const int n = threadIdx.x;
    size_t dbase = ((size_t)bh * CH + c) * HD + n;
    float AD = aD[dbase], cmx = aCM[dbase];
    size_t base = ((size_t)bh * TT + (size_t)c * CL) * HD + n;
    float* outc = c1f + (size_t)bh * TT + c * CL;
    float* outi = invd + (size_t)bh * TT + c * CL;

    for (int s = 0; s < CL; s++) {
        float kn = Kf[base + (size_t)s * HD];
        float qn = Qf2[base + (size_t)s * HD];
        float mn = flog2(kn + EPSF);
        AD += fexp2(fmaf(kn, LOG2EF, mn));
        cmx = fmaxf(cmx, kn + EPSF);
        float t1 = qn * flog2(cmx);
        float t2 = qn * flog2(AD);
#pragma unroll
        for (int off = 1; off <= 32; off <<= 1) {
            t1 += __shfl_xor(t1, off);
            t2 += __shfl_xor(t2, off);
        }
        if (n == 0) {
            outc[s] = t1;
            outi[s] = 1.0f / (t2 - t1 + EPSF);
        }
    }
}

// ---------------- Kernel 5: within-chunk rescan + output Y (bf16) -------------
__launch_bounds__(256)
__global__ void k_chunk_out(const float* __restrict__ Kf, const float* __restrict__ Vv2,
                            const float* __restrict__ Qf2, const float* __restrict__ aA,
                            const float* __restrict__ c1f, const float* __restrict__ invd,
                            const float* __restrict__ lsharp, ushort_t* __restrict__ Ymb)
{
    const int c = blockIdx.x, hh = blockIdx.y, bb = blockIdx.z;
    const int bh = bb * NH + hh;
    const int tid = threadIdx.x;

    __shared__ __align__(16) float sK[CL * HD];
    __shared__ __align__(16) float sV2[CL * HD];
    __shared__ __align__(16) float sM02[CL * HD];
    __shared__ __align__(16) float sQ2[CL * HD];

    size_t base = ((size_t)bh * TT + (size_t)c * CL) * HD;
    const float4* K4 = (const float4*)(Kf + base);
    const float4* V4 = (const float4*)(Vv2 + base);
    const float4* Q4 = (const float4*)(Qf2 + base);
#pragma unroll
    for (int r = 0; r < 2; r++) {
        int f = tid + 256 * r;
        float4 kv = K4[f];
        ((float4*)sK)[f] = kv;
        float4 mm;
        mm.x = flog2(kv.x + EPSF); mm.y = flog2(kv.y + EPSF);
        mm.z = flog2(kv.z + EPSF); mm.w = flog2(kv.w + EPSF);
        ((float4*)sM02)[f] = mm;
        ((float4*)sV2)[f] = V4[f];
        ((float4*)sQ2)[f] = Q4[f];
    }
    __syncthreads();

    const int lane = tid & 63, w = tid >> 6;
    const int g = lane >> 3, qil = lane & 7;
    const int qA = w * 8 + qil, qB = qA + 32;
    const int p0 = g * 8;

    float A[8], Bq[8];
    size_t abase = ((size_t)bh * CH + c) * 4096;
#pragma unroll
    for (int j = 0; j < 8; j++) {
        A[j]  = aA[abase + (size_t)(p0 + j) * HD + qA];
        Bq[j] = aA[abase + (size_t)(p0 + j) * HD + qB];
    }
    const float sharp = expf(lsharp[hh]);
    const float invT = 1.0f / (float)TT;
    const float* c1p = c1f + (size_t)bh * TT + c * CL;
    const float* ivp = invd + (size_t)bh * TT + c * CL;

    for (int s = 0; s < CL; s++) {
        float kqA = sK[s * HD + qA];
        float kqB = sK[s * HD + qB];
        float partA = 0.f, partB = 0.f;
#pragma unroll
        for (int j4 = 0; j4 < 2; j4++) {
            float4 vv = *(const float4*)&sV2[s * HD + p0 + j4 * 4];
            float4 mm = *(const float4*)&sM02[s * HD + p0 + j4 * 4];
            float4 qv = *(const float4*)&sQ2[s * HD + p0 + j4 * 4];
#define STEP(comp, jj) { \
            A[jj]  += fexp2(fmaf(vv.comp, kqA, mm.comp)); \
            partA = fmaf(qv.comp, flog2(A[jj]), partA); \
            Bq[jj] += fexp2(fmaf(vv.comp, kqB, mm.comp)); \
            partB = fmaf(qv.comp, flog2(Bq[jj]), partB); }
            STEP(x, j4 * 4 + 0)
            STEP(y, j4 * 4 + 1)
            STEP(z, j4 * 4 + 2)
            STEP(w, j4 * 4 + 3)
#undef STEP
        }
        partA += __shfl_xor(partA, 8);
        partA += __shfl_xor(partA, 16);
        partA += __shfl_xor(partA, 32);
        partB += __shfl_xor(partB, 8);
        partB += __shfl_xor(partB, 16);
        partB += __shfl_xor(partB, 32);

        float c1v = c1p[s], iv = ivp[s];
        int tg = c * CL + s;
        float scale = (float)(tg + 1) * invT;
        float yA = (partA - c1v) * iv;
        float yB = (partB - c1v) * iv;
        float oA = copysignf(fexp2(sharp * flog2(fabsf(yA))), yA) * scale;
        float oB = copysignf(fexp2(sharp * flog2(fabsf(yB))), yB) * scale;
        if (g == 0) {
            ushort_t* yrow = Ymb + ((size_t)(bb * TT + tg)) * DIM + hh * HD;
            yrow[qA] = f2bf(oA);
            yrow[qB] = f2bf(oB);
        }
    }
}

// ---------------- Kernel 6: output projection via MFMA (single bf16) ----------
__launch_bounds__(256)
__global__ void k_gemm_out(const ushort_t* __restrict__ Ymb, const ushort_t* __restrict__ wTo,
                           const float* __restrict__ bias, float* __restrict__ out)
{
    const int colBase = blockIdx.x * 64;
    const int rowBase = blockIdx.y * 64;

    const int tid = threadIdx.x;
    const int w16 = (tid >> 6) * 16;
    const int l = tid & 63;
    const int m = l & 15, g = l >> 4;

    const ushort_t* ax = Ymb + (size_t)(rowBase + w16 + m) * DIM + g * 8;
    const ushort_t* bw = wTo + (size_t)(colBase + m) * DIM + g * 8;

    f32x4 acc[4] = { {0,0,0,0}, {0,0,0,0}, {0,0,0,0}, {0,0,0,0} };

    for (int k0 = 0; k0 < DIM; k0 += 32) {
        bf16x8 a = *(const bf16x8*)(ax + k0);
#pragma unroll
        for (int n = 0; n < 4; n++) {
            bf16x8 b = *(const bf16x8*)(bw + (size_t)n * 16 * DIM + k0);
            acc[n] = __builtin_amdgcn_mfma_f32_16x16x32_bf16(a, b, acc[n], 0, 0, 0);
        }
    }

#pragma unroll
    for (int n = 0; n < 4; n++) {
        int c = colBase + n * 16 + m;
        float bval = bias[c];
#pragma unroll
        for (int r = 0; r < 4; r++) {
            int rr = rowBase + w16 + g * 4 + r;
            out[(size_t)rr * DIM + c] = acc[n][r] + bval;
        }
    }
}

extern "C" void kernel_launch(void* const* d_in, const int* in_sizes, int n_in,
                              void* d_out, int out_size, void* d_ws, size_t ws_size,
                              hipStream_t stream)
{
    const float* x  = (const float*)d_in[0];
    const float* wq = (const float*)d_in[1];
    const float* bq = (const float*)d_in[2];
    const float* wk = (const float*)d_in[3];
    const float* bk = (const float*)d_in[4];
    const float* wv = (const float*)d_in[5];
    const float* bv = (const float*)d_in[6];
    const float* wo = (const float*)d_in[7];
    const float* bo = (const float*)d_in[8];
    const float* lb = (const float*)d_in[9];
    const float* lt = (const float*)d_in[10];
    const float* ls = (const float*)d_in[11];

    const int B  = in_sizes[0] / (TT * DIM);   // 2
    const int BH = B * NH;                     // 16

    float* ws = (float*)d_ws;
    const size_t nQ = (size_t)BH * TT * HD;      // 1,048,576 floats
    float* Qf2 = ws;
    float* Kf  = Qf2 + nQ;
    float* Vv2 = Kf + nQ;
    float* region = Vv2 + nQ;                    // phase-aliased region

    // phase 1-2 (cvt + qkv): bf16 staging lives in [region .. region+1.79M fl)
    ushort_t* xh  = (ushort_t*)region;                                  // B*TT*DIM bf16
    ushort_t* xl  = xh + (size_t)B * TT * DIM;
    ushort_t* wTh = (ushort_t*)(region + (size_t)B * TT * DIM);         // 3*DIM*DIM bf16
    ushort_t* wTl = wTh + (size_t)3 * DIM * DIM;
    // phase 3+ : scan state overwrites the staging area
    ushort_t* Ymb = (ushort_t*)region;                                  // B*TT*DIM bf16
    float* aA  = region + (size_t)B * TT * DIM;                         // BH*CH*4096
    float* aD  = aA  + (size_t)BH * CH * 4096;
    float* aCM = aD  + (size_t)BH * CH * HD;
    float* c1f = aCM + (size_t)BH * CH * HD;
    float* invd= c1f + (size_t)BH * TT;
    ushort_t* wTo = (ushort_t*)(invd + (size_t)BH * TT);                // persists to end

    k_cvt_x<<<(B * TT * DIM) / 1024, 256, 0, stream>>>(x, xh, xl);

    dim3 gw(DIM / 64, DIM / 128, 4);
    k_cvt_w<<<gw, 256, 0, stream>>>(wq, wk, wv, wo, wTh, wTl, wTo);

    dim3 g1(NH, (B * TT) / 64, 3);
    k_gemm_qkv<<<g1, 256, 0, stream>>>(xh, xl, wTh, wTl, bq, bk, bv, lb, lt, Qf2, Kf, Vv2);

    dim3 g2(CH * 2, NH, B);
    k_chunk_reduce<<<g2, 256, 0, stream>>>(Kf, Vv2, aA, aD, aCM);

    int ntot = BH * 4096 + 2 * BH * 64;
    k_scan_agg<<<(ntot + 255) / 256, 256, 0, stream>>>(aA, aD, aCM, BH);

    dim3 g4(CH, NH, B);
    k_den<<<g4, 64, 0, stream>>>(Kf, Qf2, aD, aCM, c1f, invd);

    k_chunk_out<<<g4, 256, 0, stream>>>(Kf, Vv2, Qf2, aA, c1f, invd, ls, Ymb);

    dim3 g6(DIM / 64, (B * TT) / 64);
    k_gemm_out<<<g6, 256, 0, stream>>>(Ymb, wTo, bo, (float*)d_out);
}